// Round 1
// baseline (247.702 us; speedup 1.0000x reference)
//
#include <hip/hip_runtime.h>

#define BATCH 2048
#define VOCAB 256
#define KDIM 16384
#define BM 64
#define BK 64
#define KCHUNK 1024
#define NT (KCHUNK / BK)     // 16 K-steps per chunk
#define NKCH (KDIM / KCHUNK) // 16 K-chunks (grid.y)
#define LN10 2.302585092994046f

typedef __attribute__((ext_vector_type(8))) short short8;
typedef __attribute__((ext_vector_type(4))) float f32x4;

__device__ __forceinline__ unsigned short f2bf_rne(float f) {
  unsigned int u = __float_as_uint(f);
  u += 0x7fffu + ((u >> 16) & 1u);
  return (unsigned short)(u >> 16);
}
// binary values are exactly 0.0f/1.0f -> truncation is exact
__device__ __forceinline__ unsigned int pack2(float lo, float hi) {
  return (__float_as_uint(lo) >> 16) | (__float_as_uint(hi) & 0xffff0000u);
}

__device__ __forceinline__ void async16(void* lds, const void* g) {
  __builtin_amdgcn_global_load_lds(
      (const __attribute__((address_space(1))) unsigned int*)g,
      (__attribute__((address_space(3))) unsigned int*)lds, 16, 0, 0);
}

// ---------------- log_w precompute: logw = bf16(log(10*sigmoid(raw))) -------
__global__ __launch_bounds__(256) void k_logw(const float* __restrict__ raw,
                                              unsigned short* __restrict__ logw) {
  int i = blockIdx.x * 256 + threadIdx.x; // float4 index, exact grid
  float4 x = ((const float4*)raw)[i];
  // log(10*sigmoid(x)) = log10 - log1p(exp(-x)); x in (-1,1), no overflow
  ushort4 r;
  r.x = f2bf_rne(LN10 - log1pf(expf(-x.x)));
  r.y = f2bf_rne(LN10 - log1pf(expf(-x.y)));
  r.z = f2bf_rne(LN10 - log1pf(expf(-x.z)));
  r.w = f2bf_rne(LN10 - log1pf(expf(-x.w)));
  ((ushort4*)logw)[i] = r;
}

// ---------------- main K-split MFMA GEMM ------------------------------------
// grid (BATCH/BM, NKCH), 256 threads (4 waves), dyn LDS 80 KB.
// LDS layout (bf16, XOR-swizzled rows of 128 B): A[2][64][64], B[2][256][64]
// phys_byte(row,k) = row*128 + ((k*2) ^ ((row&7)<<4))
__global__ __launch_bounds__(256, 2) void k_gemm(
    const float* __restrict__ binary, const unsigned short* __restrict__ logw,
    float* __restrict__ accb, float* __restrict__ nact) {
  extern __shared__ char smem[];
  char* const Ab[2] = {smem, smem + 8192};
  char* const Bb[2] = {smem + 16384, smem + 16384 + 32768};

  const int tid = threadIdx.x;
  const int wv = tid >> 6;
  const int lane = tid & 63;
  const int l15 = lane & 15;
  const int lhi = lane >> 4;
  const int m0 = blockIdx.x * BM;
  const int k0 = blockIdx.y * KCHUNK;

  // A staging: thread -> (row = l15 + wv*16, 16-float chunk = lhi)
  const int s_row = l15 + wv * 16;
  const int s_ch = lhi;
  const float* a_src = binary + (size_t)(m0 + s_row) * KDIM + k0 + s_ch * 16;
  const int aw0 = s_row * 128 + ((s_ch * 32) ^ ((s_row & 7) << 4));
  const int aw1 = aw0 ^ 16;

  // B staging via global_load_lds: linear LDS dest, pre-swizzled global src.
  // pass i: lane -> row v = wv*64 + i*8 + (lane>>3), k = ((lane&7)^(lane>>3))*8
  const int b_v0 = wv * 64 + (lane >> 3);
  const int b_kl = ((lane & 7) ^ (lane >> 3)) << 3;
  const unsigned short* b_src = logw + (size_t)b_v0 * KDIM + k0 + b_kl;

  float4 areg[4];
  float asum = 0.f;
  f32x4 acc[4][4];
#pragma unroll
  for (int m = 0; m < 4; ++m)
#pragma unroll
    for (int n = 0; n < 4; ++n) acc[m][n] = f32x4{0.f, 0.f, 0.f, 0.f};

  auto A_LOAD = [&](int t) {
    const float4* p = (const float4*)(a_src + t * BK);
    areg[0] = p[0]; areg[1] = p[1]; areg[2] = p[2]; areg[3] = p[3];
  };
  auto B_STAGE = [&](int t, char* B) {
#pragma unroll
    for (int i = 0; i < 8; ++i)
      async16(B + (wv * 8 + i) * 1024, b_src + (size_t)i * 8 * KDIM + t * BK);
  };
  auto A_WRITE = [&](char* A) {
#pragma unroll
    for (int j = 0; j < 4; ++j)
      asum += areg[j].x + areg[j].y + areg[j].z + areg[j].w;
    uint4 u0, u1;
    u0.x = pack2(areg[0].x, areg[0].y); u0.y = pack2(areg[0].z, areg[0].w);
    u0.z = pack2(areg[1].x, areg[1].y); u0.w = pack2(areg[1].z, areg[1].w);
    u1.x = pack2(areg[2].x, areg[2].y); u1.y = pack2(areg[2].z, areg[2].w);
    u1.z = pack2(areg[3].x, areg[3].y); u1.w = pack2(areg[3].z, areg[3].w);
    *(uint4*)(A + aw0) = u0;
    *(uint4*)(A + aw1) = u1;
  };
  auto COMPUTE = [&](const char* A, const char* B) {
    const int sw = (l15 & 7) << 4;
#pragma unroll
    for (int ks = 0; ks < 2; ++ks) {
      const int koff = (ks * 64 + lhi * 16) ^ sw;
      short8 af[4], bfr[4];
#pragma unroll
      for (int m = 0; m < 4; ++m)
        af[m] = *(const short8*)(A + (m * 16 + l15) * 128 + koff);
#pragma unroll
      for (int n = 0; n < 4; ++n)
        bfr[n] = *(const short8*)(B + (wv * 64 + n * 16 + l15) * 128 + koff);
#pragma unroll
      for (int m = 0; m < 4; ++m)
#pragma unroll
        for (int n = 0; n < 4; ++n)
          acc[m][n] = __builtin_amdgcn_mfma_f32_16x16x32_bf16(af[m], bfr[n],
                                                              acc[m][n], 0, 0, 0);
    }
  };

  // prologue: stage tile 0 into buffer 0
  A_LOAD(0);
  B_STAGE(0, Bb[0]);
  A_WRITE(Ab[0]);
  __syncthreads(); // drains vmcnt (B in LDS) + lgkmcnt (A writes)

  int p = 0;
#pragma unroll
  for (int t = 0; t < NT; ++t) {
    if (t + 1 < NT) {
      A_LOAD(t + 1);
      B_STAGE(t + 1, Bb[p ^ 1]);
    }
    COMPUTE(Ab[p], Bb[p]);
    if (t + 1 < NT) A_WRITE(Ab[p ^ 1]);
    __syncthreads();
    p ^= 1;
  }

  // n_active partial: 4 threads per row are lanes {l, l^16, l^32, l^48}
  float s = asum;
  s += __shfl_xor(s, 16, 64);
  s += __shfl_xor(s, 32, 64);
  if (lane < 16) atomicAdd(&nact[m0 + wv * 16 + l15], s);

  // K-split reduction: fp32 atomics into output accumulator
  // C/D layout (m89/m91): col = lane&15, row = (lane>>4)*4 + i
#pragma unroll
  for (int m = 0; m < 4; ++m)
#pragma unroll
    for (int n = 0; n < 4; ++n)
#pragma unroll
      for (int i = 0; i < 4; ++i) {
        int r = m0 + m * 16 + lhi * 4 + i;
        int c = wv * 64 + n * 16 + l15;
        atomicAdd(&accb[(size_t)r * VOCAB + c], acc[m][n][i]);
      }
}

// ---------------- epilogue: logits = exp(log_sum / max(n_active,1)) ---------
__global__ __launch_bounds__(256) void k_out(float* __restrict__ io,
                                             const float* __restrict__ nact) {
  int b = blockIdx.x;
  int v = threadIdx.x;
  float n = fmaxf(nact[b], 1.0f);
  size_t idx = (size_t)b * VOCAB + v;
  io[idx] = expf(io[idx] / n);
}

extern "C" void kernel_launch(void* const* d_in, const int* in_sizes, int n_in,
                              void* d_out, int out_size, void* d_ws, size_t ws_size,
                              hipStream_t stream) {
  const float* binary = (const float*)d_in[0];
  const float* raw = (const float*)d_in[1];
  float* out = (float*)d_out;
  char* ws = (char*)d_ws;
  unsigned short* logw = (unsigned short*)ws;             // 8 MB
  float* nact = (float*)(ws + (size_t)8 * 1024 * 1024);   // 8 KB

  hipMemsetAsync(out, 0, (size_t)BATCH * VOCAB * sizeof(float), stream);
  hipMemsetAsync(nact, 0, BATCH * sizeof(float), stream);

  k_logw<<<(VOCAB * KDIM / 4) / 256, 256, 0, stream>>>(raw, logw);

  dim3 g(BATCH / BM, NKCH);
  k_gemm<<<g, 256, 81920, stream>>>(binary, logw, out, nact);

  k_out<<<BATCH, VOCAB, 0, stream>>>(out, nact);
}